// Round 6
// baseline (631.286 us; speedup 1.0000x reference)
//
#include <hip/hip_runtime.h>

#define N_Q  100000
#define N_M  5000
#define G    128
#define NC   (G * G)                 // 16384 cells
#define CS_OFF_B   64                // byte offset of cell_start[NC+1] in ws
#define SORT_OFF_B (CS_OFF_B + (NC + 1) * 4 + 12)   // 65616, 16-aligned
#define WS_NEED    (SORT_OFF_B + N_M * 16)          // 145616 B

// ---------------------------------------------------------------------------
// Build: bounding box -> 128x128 histogram -> scan -> scatter (cell-sorted
// records {x, y, ts, orig_idx}). Single 1024-thread block (~5000 pts, tiny).
// Box uses ACTUAL min/max so every point lies inside its cell rectangle
// (required for the ring lower-bound proof). Within-cell scatter order is
// nondeterministic (atomics) but the query's (d2, idx) lexicographic min is
// order-independent -> output deterministic.
// ---------------------------------------------------------------------------
__global__ __launch_bounds__(1024) void build_grid(
    const float* __restrict__ maze, const float* __restrict__ ts,
    float* __restrict__ ws)
{
    __shared__ float red[1024];
    __shared__ int   part[1024];
    __shared__ int   cnt[NC];        // 64 KB
    const int t = threadIdx.x;

    // 1) min/max of maze coords
    float mnx = 1e30f, mxx = -1e30f, mny = 1e30f, mxy = -1e30f;
    for (int i = t; i < N_M; i += 1024) {
        const float x = maze[2 * i], y = maze[2 * i + 1];
        mnx = fminf(mnx, x); mxx = fmaxf(mxx, x);
        mny = fminf(mny, y); mxy = fmaxf(mxy, y);
    }
    auto reduce = [&](float v, bool domin) -> float {
        red[t] = v; __syncthreads();
        for (int s = 512; s > 0; s >>= 1) {
            if (t < s) {
                const float o = red[t + s];
                red[t] = domin ? fminf(red[t], o) : fmaxf(red[t], o);
            }
            __syncthreads();
        }
        const float r = red[0]; __syncthreads(); return r;
    };
    mnx = reduce(mnx, true);  mxx = reduce(mxx, false);
    mny = reduce(mny, true);  mxy = reduce(mxy, false);

    // slightly inflated cell width -> floor((max-min)*inv) <= G-1 guaranteed
    const float cwx = (mxx - mnx) * (1.0f / G) * (1.0f + 1e-5f);
    const float cwy = (mxy - mny) * (1.0f / G) * (1.0f + 1e-5f);
    const float ivx = 1.0f / cwx, ivy = 1.0f / cwy;
    if (t == 0) {
        ws[0] = mnx; ws[1] = mny; ws[2] = cwx;
        ws[3] = cwy; ws[4] = ivx; ws[5] = ivy;
    }

    // 2) histogram
    for (int i = t; i < NC; i += 1024) cnt[i] = 0;
    __syncthreads();
    for (int i = t; i < N_M; i += 1024) {
        const float x = maze[2 * i], y = maze[2 * i + 1];
        const int cx = min(G - 1, max(0, (int)((x - mnx) * ivx)));
        const int cy = min(G - 1, max(0, (int)((y - mny) * ivy)));
        atomicAdd(&cnt[cy * G + cx], 1);
    }
    __syncthreads();

    // 3) exclusive scan (16 cells/thread serial + Hillis-Steele over partials)
    int* cs = (int*)((char*)ws + CS_OFF_B);
    const int base = t * 16;
    int loc[16], sum = 0;
    #pragma unroll
    for (int j = 0; j < 16; ++j) { loc[j] = sum; sum += cnt[base + j]; }
    part[t] = sum; __syncthreads();
    for (int s = 1; s < 1024; s <<= 1) {
        const int v = (t >= s) ? part[t - s] : 0;
        __syncthreads();
        part[t] += v;
        __syncthreads();
    }
    const int excl = part[t] - sum;
    #pragma unroll
    for (int j = 0; j < 16; ++j) cs[base + j] = excl + loc[j];
    if (t == 0) cs[NC] = N_M;
    __syncthreads();
    // reuse cnt as scatter cursors
    #pragma unroll
    for (int j = 0; j < 16; ++j) cnt[base + j] = excl + loc[j];
    __syncthreads();

    // 4) scatter cell-sorted records
    float4* sorted = (float4*)((char*)ws + SORT_OFF_B);
    for (int i = t; i < N_M; i += 1024) {
        const float x = maze[2 * i], y = maze[2 * i + 1];
        const int cx = min(G - 1, max(0, (int)((x - mnx) * ivx)));
        const int cy = min(G - 1, max(0, (int)((y - mny) * ivy)));
        const int pos = atomicAdd(&cnt[cy * G + cx], 1);
        float4 e;
        e.x = x; e.y = y; e.z = ts[i]; e.w = __int_as_float(i);
        sorted[pos] = e;
    }
}

// ---------------------------------------------------------------------------
// Query: ring expansion, exact numpy arithmetic per candidate, lexicographic
// (d2, orig_idx) min (== numpy argmin first-occurrence, visit-order-free).
// Stop when the ring-(r+1) lower bound (distance to the inner rect of cells
// [cx-r..cx+r]^2, with >1-ulp conservative slack) exceeds best.
// ---------------------------------------------------------------------------
__global__ __launch_bounds__(256) void grid_query(
    const float* __restrict__ q, const float* __restrict__ ws,
    float* __restrict__ out)
{
    const int qi = blockIdx.x * 256 + threadIdx.x;
    if (qi >= N_Q) return;

    const float mnx = ws[0], mny = ws[1], cwx = ws[2];
    const float cwy = ws[3], ivx = ws[4], ivy = ws[5];
    const int*    cs     = (const int*)((const char*)ws + CS_OFF_B);
    const float4* sorted = (const float4*)((const char*)ws + SORT_OFF_B);

    const float2 Q = ((const float2*)q)[qi];
    const float qx = Q.x, qy = Q.y;
    const int cx = min(G - 1, max(0, (int)((qx - mnx) * ivx)));
    const int cy = min(G - 1, max(0, (int)((qy - mny) * ivy)));

    float bd2 = 3.4e38f;
    int bidx = 0x7fffffff, bsp = 0;

    auto scan_cell = [&](int cell) {
        const int s = cs[cell], e = cs[cell + 1];
        for (int p = s; p < e; ++p) {
            const float4 c = sorted[p];
            // numpy-exact: dx=rn(qx-px); d2=rn(rn(dx*dx)+rn(dy*dy)); no FMA.
            const float dx = __fsub_rn(qx, c.x);
            const float dy = __fsub_rn(qy, c.y);
            const float d2 = __fadd_rn(__fmul_rn(dx, dx), __fmul_rn(dy, dy));
            const int idx = __float_as_int(c.w);
            if (d2 < bd2 || (d2 == bd2 && idx < bidx)) {
                bd2 = d2; bidx = idx; bsp = p;
            }
        }
    };

    for (int r = 0;; ++r) {
        const int x0 = max(0, cx - r), x1 = min(G - 1, cx + r);
        const int y0 = max(0, cy - r), y1 = min(G - 1, cy + r);
        if (r == 0) {
            scan_cell(cy * G + cx);
        } else {
            if (cy - r >= 0)     { const int rb = (cy - r) * G; for (int x = x0; x <= x1; ++x) scan_cell(rb + x); }
            if (cy + r <= G - 1) { const int rb = (cy + r) * G; for (int x = x0; x <= x1; ++x) scan_cell(rb + x); }
            const int yy0 = max(y0, cy - r + 1), yy1 = min(y1, cy + r - 1);
            if (cx - r >= 0)     for (int y = yy0; y <= yy1; ++y) scan_cell(y * G + cx - r);
            if (cx + r <= G - 1) for (int y = yy0; y <= yy1; ++y) scan_cell(y * G + cx + r);
        }
        // rings >= r+1 lie outside the world-rect of cells [cx-r..cx+r]^2
        const float Xlo = mnx + (float)(cx - r) * cwx;
        const float Xhi = mnx + (float)(cx + r + 1) * cwx;
        const float Ylo = mny + (float)(cy - r) * cwy;
        const float Yhi = mny + (float)(cy + r + 1) * cwy;
        float lb = fminf(fminf(qx - Xlo, Xhi - qx), fminf(qy - Ylo, Yhi - qy));
        lb = lb * 0.9999f - 1e-6f;          // conservative: covers all fp slop
        if (lb > 0.0f && lb * lb > bd2) break;
        if (r > 2 * G) break;               // safety (unreachable)
    }

    const float4 bw = sorted[bsp];
    out[2 * qi]       = bw.x;
    out[2 * qi + 1]   = bw.y;
    out[2 * N_Q + qi] = bw.z;
}

// ---------------------------------------------------------------------------
// Fallback (proven R4 kernel, no workspace needed) if ws is too small.
// ---------------------------------------------------------------------------
#define FCH   8
#define FLCH  640
#define FNP   (FCH * FLCH)
#define FSUB  16
#define FNSUB (FLCH / FSUB)
#define FFPS  (FSUB / 2)

typedef float v2f __attribute__((ext_vector_type(2)));
#define FPK_ADD(d, a, b) asm("v_pk_add_f32 %0, %1, %2" : "=v"(d) : "v"(a), "v"(b))
#define FPK_MUL(d, a, b) asm("v_pk_mul_f32 %0, %1, %2" : "=v"(d) : "v"(a), "v"(b))
#define FMIN3(d, a, b, c) asm("v_min3_f32 %0, %1, %2, %3" : "=v"(d) : "v"(a), "v"(b), "v"(c))

__global__ __launch_bounds__(256) void nn1_fallback(
    const float* __restrict__ q, const float* __restrict__ maze,
    const float* __restrict__ ts, float* __restrict__ out)
{
    __shared__ float4 sm[(FLCH / 2) * FCH];
    const float2* mz = (const float2*)maze;
    for (int i = threadIdx.x; i < FNP; i += 256) {
        const int c = i / FLCH, k = i - c * FLCH;
        float px = 1e30f, py = 1e30f;
        if (i < N_M) { float2 p = mz[i]; px = p.x; py = p.y; }
        ((float2*)sm)[((k >> 1) * FCH + c) * 2 + (k & 1)] = make_float2(-px, -py);
    }
    __syncthreads();
    const int t = threadIdx.x, lane = t & 63, g = lane >> 3, c = lane & 7;
    const int qb = blockIdx.x * 64 + (t >> 6) * 16 + g;
    const int qi0 = qb, qi1 = qb + 8;
    const float2 qa = ((const float2*)q)[qi0 < N_Q ? qi0 : N_Q - 1];
    const float2 qc = ((const float2*)q)[qi1 < N_Q ? qi1 : N_Q - 1];
    const v2f qva = { qa.x, qa.y }, qvb = { qc.x, qc.y };
    const float4* base = &sm[c];
    float run0 = 3.4e38f, run1 = 3.4e38f; int bb0 = 0, bb1 = 0;
    for (int b = 0; b < FNSUB; ++b) {
        float bm0 = 3.4e38f, bm1 = 3.4e38f;
        #pragma unroll
        for (int fi = 0; fi < FFPS; ++fi) {
            const float4 pp = base[(b * FFPS + fi) * FCH];
            const v2f p0 = { pp.x, pp.y }, p1 = { pp.z, pp.w };
            v2f e0, s0, e1, s1, f0, u0, f1, u1;
            FPK_ADD(e0, qva, p0); FPK_MUL(s0, e0, e0);
            FPK_ADD(e1, qva, p1); FPK_MUL(s1, e1, e1);
            FPK_ADD(f0, qvb, p0); FPK_MUL(u0, f0, f0);
            FPK_ADD(f1, qvb, p1); FPK_MUL(u1, f1, f1);
            const float d0a = __fadd_rn(s0.x, s0.y), d1a = __fadd_rn(s1.x, s1.y);
            const float d0b = __fadd_rn(u0.x, u0.y), d1b = __fadd_rn(u1.x, u1.y);
            FMIN3(bm0, d0a, d1a, bm0); FMIN3(bm1, d0b, d1b, bm1);
        }
        if (bm0 < run0) { run0 = bm0; bb0 = b; }
        if (bm1 < run1) { run1 = bm1; bb1 = b; }
    }
    auto rescan = [&](float best, int bbx, v2f qv) -> int {
        int midx = 0x7fffffff;
        #pragma unroll
        for (int fi = 0; fi < FFPS; ++fi) {
            const float4 pp = base[(bbx * FFPS + fi) * FCH];
            const v2f p0 = { pp.x, pp.y }, p1 = { pp.z, pp.w };
            v2f e0, s0, e1, s1;
            FPK_ADD(e0, qv, p0); FPK_MUL(s0, e0, e0);
            FPK_ADD(e1, qv, p1); FPK_MUL(s1, e1, e1);
            const float d0 = __fadd_rn(s0.x, s0.y), d1 = __fadd_rn(s1.x, s1.y);
            const int gi = c * FLCH + bbx * FSUB + fi * 2;
            if (d0 == best && gi < midx) midx = gi;
            if (d1 == best && gi + 1 < midx) midx = gi + 1;
        }
        return midx;
    };
    int mi0 = rescan(run0, bb0, qva), mi1 = rescan(run1, bb1, qvb);
    float v0 = run0, v1 = run1;
    #pragma unroll
    for (int s = 1; s < FCH; s <<= 1) {
        const float o0 = __shfl_xor(v0, s); const int j0 = __shfl_xor(mi0, s);
        if (o0 < v0 || (o0 == v0 && j0 < mi0)) { v0 = o0; mi0 = j0; }
        const float o1 = __shfl_xor(v1, s); const int j1 = __shfl_xor(mi1, s);
        if (o1 < v1 || (o1 == v1 && j1 < mi1)) { v1 = o1; mi1 = j1; }
    }
    if (c == 0) {
        mi0 = mi0 < N_M ? mi0 : N_M - 1; mi1 = mi1 < N_M ? mi1 : N_M - 1;
        if (qi0 < N_Q) { const float2 bp = mz[mi0];
            out[2*qi0] = bp.x; out[2*qi0+1] = bp.y; out[2*N_Q+qi0] = ts[mi0]; }
        if (qi1 < N_Q) { const float2 bp = mz[mi1];
            out[2*qi1] = bp.x; out[2*qi1+1] = bp.y; out[2*N_Q+qi1] = ts[mi1]; }
    }
}

extern "C" void kernel_launch(void* const* d_in, const int* in_sizes, int n_in,
                              void* d_out, int out_size, void* d_ws, size_t ws_size,
                              hipStream_t stream) {
    const float* q    = (const float*)d_in[0];  // euclidean_data [N,2]
    const float* maze = (const float*)d_in[1];  // maze_points   [M,2]
    const float* ts   = (const float*)d_in[2];  // ts_proj       [M]
    float* out = (float*)d_out;                 // [N*2] proj_pos ++ [N] linear_pos

    if (ws_size >= (size_t)WS_NEED) {
        build_grid<<<1, 1024, 0, stream>>>(maze, ts, (float*)d_ws);
        grid_query<<<(N_Q + 255) / 256, 256, 0, stream>>>(q, (const float*)d_ws, out);
    } else {
        nn1_fallback<<<(N_Q + 63) / 64, 256, 0, stream>>>(q, maze, ts, out);
    }
}

// Round 7
// 76.814 us; speedup vs baseline: 8.2183x; 8.2183x over previous
//
#include <hip/hip_runtime.h>

#define N_Q  100000
#define N_M  5000
#define G    64
#define NC   (G * G)                 // 4096 cells
#define RMAX 4                       // ring cap; unresolved -> brute overflow
#define CS_OFF_B   64
#define SORT_OFF_B (CS_OFF_B + 16400)         // 16464 (cs: 4097*4=16388, padded)
#define OVF_OFF_B  (SORT_OFF_B + N_M * 16)    // 96464
#define WS_NEED    (OVF_OFF_B + N_Q * 4)      // 496464 B

// ============================================================================
// build_grid: bbox -> 64x64 histogram -> scan -> scatter {x,y,ts,idx} records.
// One 1024-thread block. Box = actual min/max with inflated cell width -> every
// point's raw cell index lands in [0,G) (no clamping for points) -> each point
// provably lies inside its cell rect (ring lower-bound proof). Scatter order is
// nondeterministic, but queries use order-free (d2,idx) lex-min -> deterministic.
// ============================================================================
__global__ __launch_bounds__(1024) void build_grid(
    const float* __restrict__ maze, const float* __restrict__ ts,
    float* __restrict__ ws)
{
    __shared__ float red[1024];
    __shared__ int   part[1024];
    __shared__ int   cnt[NC];        // 16 KB
    const int t = threadIdx.x;
    if (t == 0) ((int*)ws)[8] = 0;   // reset overflow counter (every call)

    float mnx = 1e30f, mxx = -1e30f, mny = 1e30f, mxy = -1e30f;
    for (int i = t; i < N_M; i += 1024) {
        const float x = maze[2 * i], y = maze[2 * i + 1];
        mnx = fminf(mnx, x); mxx = fmaxf(mxx, x);
        mny = fminf(mny, y); mxy = fmaxf(mxy, y);
    }
    auto reduce = [&](float v, bool domin) -> float {
        red[t] = v; __syncthreads();
        for (int s = 512; s > 0; s >>= 1) {
            if (t < s) {
                const float o = red[t + s];
                red[t] = domin ? fminf(red[t], o) : fmaxf(red[t], o);
            }
            __syncthreads();
        }
        const float r = red[0]; __syncthreads(); return r;
    };
    mnx = reduce(mnx, true);  mxx = reduce(mxx, false);
    mny = reduce(mny, true);  mxy = reduce(mxy, false);

    float cwx = (mxx - mnx) * (1.0f / G) * (1.0f + 1e-5f);
    float cwy = (mxy - mny) * (1.0f / G) * (1.0f + 1e-5f);
    if (!(cwx > 0.0f)) cwx = 1.0f;   // degenerate box: all pts in column 0
    if (!(cwy > 0.0f)) cwy = 1.0f;
    const float ivx = 1.0f / cwx, ivy = 1.0f / cwy;
    if (t == 0) {
        ws[0] = mnx; ws[1] = mny; ws[2] = cwx;
        ws[3] = cwy; ws[4] = ivx; ws[5] = ivy;
    }

    for (int i = t; i < NC; i += 1024) cnt[i] = 0;
    __syncthreads();
    for (int i = t; i < N_M; i += 1024) {
        const float x = maze[2 * i], y = maze[2 * i + 1];
        const int cx = min(G - 1, max(0, (int)((x - mnx) * ivx)));
        const int cy = min(G - 1, max(0, (int)((y - mny) * ivy)));
        atomicAdd(&cnt[cy * G + cx], 1);
    }
    __syncthreads();

    // exclusive scan: 4 cells/thread + Hillis-Steele over 1024 partials
    int* cs = (int*)((char*)ws + CS_OFF_B);
    const int base = t * 4;
    int loc[4], sum = 0;
    #pragma unroll
    for (int j = 0; j < 4; ++j) { loc[j] = sum; sum += cnt[base + j]; }
    part[t] = sum; __syncthreads();
    for (int s = 1; s < 1024; s <<= 1) {
        const int v = (t >= s) ? part[t - s] : 0;
        __syncthreads();
        part[t] += v;
        __syncthreads();
    }
    const int excl = part[t] - sum;
    #pragma unroll
    for (int j = 0; j < 4; ++j) cs[base + j] = excl + loc[j];
    if (t == 0) cs[NC] = N_M;
    __syncthreads();
    #pragma unroll
    for (int j = 0; j < 4; ++j) cnt[base + j] = excl + loc[j];  // cursors
    __syncthreads();

    float4* sorted = (float4*)((char*)ws + SORT_OFF_B);
    for (int i = t; i < N_M; i += 1024) {
        const float x = maze[2 * i], y = maze[2 * i + 1];
        const int cx = min(G - 1, max(0, (int)((x - mnx) * ivx)));
        const int cy = min(G - 1, max(0, (int)((y - mny) * ivy)));
        const int pos = atomicAdd(&cnt[cy * G + cx], 1);
        float4 e; e.x = x; e.y = y; e.z = ts[i]; e.w = __int_as_float(i);
        sorted[pos] = e;
    }
}

// ============================================================================
// grid_query: ring expansion capped at RMAX. Exact numpy IEEE sequence per
// candidate; (d2, orig_idx) lex-min == argmin first-occurrence, visit-order-
// free. Resolved -> write output. Unresolved -> push qi to overflow list.
// ============================================================================
__global__ __launch_bounds__(256) void grid_query(
    const float* __restrict__ q, float* __restrict__ ws,
    float* __restrict__ out)
{
    const int qi = blockIdx.x * 256 + threadIdx.x;
    if (qi >= N_Q) return;

    const float mnx = ws[0], mny = ws[1], cwx = ws[2];
    const float cwy = ws[3], ivx = ws[4], ivy = ws[5];
    const int*    cs     = (const int*)((const char*)ws + CS_OFF_B);
    const float4* sorted = (const float4*)((const char*)ws + SORT_OFF_B);

    const float2 Q = ((const float2*)q)[qi];
    const float qx = Q.x, qy = Q.y;
    const int cx = min(G - 1, max(0, (int)((qx - mnx) * ivx)));
    const int cy = min(G - 1, max(0, (int)((qy - mny) * ivy)));

    float bd2 = 3.4e38f;
    int bidx = 0x7fffffff, bsp = 0;

    auto scan_pts = [&](int s, int e) {
        for (int p = s; p < e; ++p) {
            const float4 c = sorted[p];
            const float dx = __fsub_rn(qx, c.x);           // numpy-exact, no FMA
            const float dy = __fsub_rn(qy, c.y);
            const float d2 = __fadd_rn(__fmul_rn(dx, dx), __fmul_rn(dy, dy));
            const int idx = __float_as_int(c.w);
            if (d2 < bd2 || (d2 == bd2 && idx < bidx)) { bd2 = d2; bidx = idx; bsp = p; }
        }
    };
    auto scan_row = [&](int rowbase, int xa, int xb) {     // contiguous cells:
        int prev = cs[rowbase + xa];                       // reuse cs loads
        for (int x = xa; x <= xb; ++x) {
            const int nxt = cs[rowbase + x + 1];
            scan_pts(prev, nxt);
            prev = nxt;
        }
    };

    bool resolved = false;
    for (int r = 0; r <= RMAX; ++r) {
        const int x0 = max(0, cx - r), x1 = min(G - 1, cx + r);
        if (r == 0) {
            scan_row(cy * G, cx, cx);
        } else {
            if (cy - r >= 0)     scan_row((cy - r) * G, x0, x1);
            if (cy + r <= G - 1) scan_row((cy + r) * G, x0, x1);
            const int yy0 = max(0, cy - r + 1), yy1 = min(G - 1, cy + r - 1);
            if (cx - r >= 0)     for (int y = yy0; y <= yy1; ++y) { const int c0 = y * G + cx - r; scan_pts(cs[c0], cs[c0 + 1]); }
            if (cx + r <= G - 1) for (int y = yy0; y <= yy1; ++y) { const int c0 = y * G + cx + r; scan_pts(cs[c0], cs[c0 + 1]); }
        }
        // all unscanned points lie outside the world-rect of cells [cx±r]x[cy±r]
        const float Xlo = mnx + (float)(cx - r) * cwx;
        const float Xhi = mnx + (float)(cx + r + 1) * cwx;
        const float Ylo = mny + (float)(cy - r) * cwy;
        const float Yhi = mny + (float)(cy + r + 1) * cwy;
        float lb = fminf(fminf(qx - Xlo, Xhi - qx), fminf(qy - Ylo, Yhi - qy));
        lb = lb * 0.9999f - 1e-6f;                 // >1-ulp conservative slack
        if (lb > 0.0f && lb * lb > bd2) { resolved = true; break; }
    }

    if (resolved) {
        const float4 bw = sorted[bsp];
        out[2 * qi]       = bw.x;
        out[2 * qi + 1]   = bw.y;
        out[2 * N_Q + qi] = bw.z;
    } else {
        int* ovfc = (int*)ws + 8;
        const int pos = atomicAdd(ovfc, 1);
        ((int*)((char*)ws + OVF_OFF_B))[pos] = qi;  // brute kernel finishes it
    }
}

// ============================================================================
// brute_overflow: one wave per unresolved query (grid-stride). 79 pts/lane,
// identical IEEE sequence, 6-round lex shuffle-reduce. List order is
// nondeterministic but each query writes only its own slot -> deterministic.
// ============================================================================
__global__ __launch_bounds__(256) void brute_overflow(
    const float* __restrict__ q, const float* __restrict__ maze,
    const float* __restrict__ ts, const float* __restrict__ ws,
    float* __restrict__ out)
{
    const int cnt = ((const int*)ws)[8];
    const int* ovl = (const int*)((const char*)ws + OVF_OFF_B);
    const int wave  = (blockIdx.x * 256 + threadIdx.x) >> 6;
    const int lane  = threadIdx.x & 63;
    const int nwave = gridDim.x * 4;

    for (int w = wave; w < cnt; w += nwave) {
        const int qi = ovl[w];
        const float qx = q[2 * qi], qy = q[2 * qi + 1];
        float bd2 = 3.4e38f; int bidx = 0x7fffffff;
        for (int p = lane; p < N_M; p += 64) {
            const float2 c = ((const float2*)maze)[p];
            const float dx = __fsub_rn(qx, c.x);
            const float dy = __fsub_rn(qy, c.y);
            const float d2 = __fadd_rn(__fmul_rn(dx, dx), __fmul_rn(dy, dy));
            if (d2 < bd2 || (d2 == bd2 && p < bidx)) { bd2 = d2; bidx = p; }
        }
        #pragma unroll
        for (int s = 1; s < 64; s <<= 1) {
            const float ob = __shfl_xor(bd2, s);
            const int   oi = __shfl_xor(bidx, s);
            if (ob < bd2 || (ob == bd2 && oi < bidx)) { bd2 = ob; bidx = oi; }
        }
        if (lane == 0) {
            out[2 * qi]       = maze[2 * bidx];
            out[2 * qi + 1]   = maze[2 * bidx + 1];
            out[2 * N_Q + qi] = ts[bidx];
        }
    }
}

// ============================================================================
// Fallback: proven R5 SMEM-stream scan (66 us, needs 40448 B ws).
// ============================================================================
#define CW   4
#define CHK  1264
#define NPAD (CW * CHK)
#define FB_WS_BYTES (NPAD * 2 * 4)

typedef float v2f __attribute__((ext_vector_type(2)));
typedef float v8f __attribute__((ext_vector_type(8)));

__global__ void setup_soa(const float* __restrict__ maze, float* __restrict__ ws) {
    const int i = blockIdx.x * 256 + threadIdx.x;
    if (i >= NPAD) return;
    const int c = i / CHK, k = i - c * CHK;
    float x = 1e30f, y = 1e30f;
    const int g = c * 1250 + k;
    if (k < 1250) { x = -maze[2 * g]; y = -maze[2 * g + 1]; }
    ws[i] = x;
    ws[NPAD + i] = y;
}

#define LDX0(D) asm volatile("s_load_dwordx8 %0, %1, 0x0"    : "=s"(D) : "s"(xb))
#define LDX1(D) asm volatile("s_load_dwordx8 %0, %1, 0x20"   : "=s"(D) : "s"(xb))
#define LDY0(D) asm volatile("s_load_dwordx8 %0, %1, 0x4f00" : "=s"(D) : "s"(xb))
#define LDY1(D) asm volatile("s_load_dwordx8 %0, %1, 0x4f20" : "=s"(D) : "s"(xb))
#define WAIT4(a,b,c,d) asm volatile("s_waitcnt lgkmcnt(0)" : "+s"(a), "+s"(b), "+s"(c), "+s"(d))

#define PSTEP(X8, Y8, J) do {                                                 \
    v2f px_ = __builtin_shufflevector(X8, X8, 2*(J), 2*(J)+1);                \
    v2f py_ = __builtin_shufflevector(Y8, Y8, 2*(J), 2*(J)+1);                \
    v2f dx_, dy_;                                                             \
    asm("v_pk_add_f32 %0, %1, %2" : "=v"(dx_) : "s"(px_), "v"(qxx));          \
    asm("v_pk_add_f32 %0, %1, %2" : "=v"(dy_) : "s"(py_), "v"(qyy));          \
    asm("v_pk_mul_f32 %0, %0, %0" : "+v"(dx_));                               \
    asm("v_pk_mul_f32 %0, %0, %0" : "+v"(dy_));                               \
    asm("v_pk_add_f32 %0, %0, %1" : "+v"(dx_) : "v"(dy_));                    \
    float a_ = dx_.x, b_ = dx_.y;                                             \
    asm("v_min3_f32 %0, %1, %2, %0" : "+v"(bm) : "v"(a_), "v"(b_));           \
} while (0)

#define COMP(X0, X1, Y0, Y1, B) do {                                          \
    PSTEP(X0, Y0, 0); PSTEP(X0, Y0, 1); PSTEP(X0, Y0, 2); PSTEP(X0, Y0, 3);   \
    PSTEP(X1, Y1, 0); PSTEP(X1, Y1, 1); PSTEP(X1, Y1, 2); PSTEP(X1, Y1, 3);   \
    bb = (bm < prev) ? (B) : bb; prev = bm;                                   \
} while (0)

__global__ __launch_bounds__(256) void nn_scan(
    const float* __restrict__ q, const float* __restrict__ maze,
    const float* __restrict__ ts, const float* __restrict__ ws,
    float* __restrict__ out)
{
    __shared__ float sval[CW][64];
    __shared__ int   sidx[CW][64];
    const int lane = threadIdx.x & 63;
    const int wv   = __builtin_amdgcn_readfirstlane((int)(threadIdx.x >> 6));
    const int qi   = blockIdx.x * 64 + lane;
    const int qc   = qi < N_Q ? qi : N_Q - 1;
    const float2 Q = ((const float2*)q)[qc];
    const v2f qxx = { Q.x, Q.x };
    const v2f qyy = { Q.y, Q.y };
    unsigned long long xb = (unsigned long long)(const void*)(ws + (size_t)wv * CHK);
    v8f ax0, ax1, ay0, ay1, bx0, bx1, by0, by1;
    LDX0(ax0); LDX1(ax1); LDY0(ay0); LDY1(ay1); xb += 64;
    float bm = 3.4e38f, prev = 3.4e38f;
    int bb = 0;
    #pragma unroll 1
    for (int k = 0; k < 39; ++k) {
        WAIT4(ax0, ax1, ay0, ay1);
        LDX0(bx0); LDX1(bx1); LDY0(by0); LDY1(by1); xb += 64;
        COMP(ax0, ax1, ay0, ay1, 2 * k);
        WAIT4(bx0, bx1, by0, by1);
        LDX0(ax0); LDX1(ax1); LDY0(ay0); LDY1(ay1); xb += 64;
        COMP(bx0, bx1, by0, by1, 2 * k + 1);
    }
    WAIT4(ax0, ax1, ay0, ay1);
    COMP(ax0, ax1, ay0, ay1, 78);
    int fk = 0x7fffffff;
    {
        const float* xs = ws + (size_t)wv * CHK + (size_t)bb * 16;
        #pragma unroll
        for (int j = 0; j < 16; ++j) {
            const float dx = __fadd_rn(Q.x, xs[j]);
            const float dy = __fadd_rn(Q.y, xs[j + NPAD]);
            const float d2 = __fadd_rn(__fmul_rn(dx, dx), __fmul_rn(dy, dy));
            if (d2 == bm) fk = min(fk, bb * 16 + j);
        }
    }
    const int kloc = fk < 1250 ? fk : 1249;
    sval[wv][lane] = bm;
    sidx[wv][lane] = wv * 1250 + kloc;
    __syncthreads();
    if (wv == 0 && qi < N_Q) {
        float bv = sval[0][lane];
        int   bg = sidx[0][lane];
        #pragma unroll
        for (int c = 1; c < CW; ++c) {
            const float v = sval[c][lane];
            const int   g = sidx[c][lane];
            if (v < bv || (v == bv && g < bg)) { bv = v; bg = g; }
        }
        const float2 bp = ((const float2*)maze)[bg];
        out[2 * qi]       = bp.x;
        out[2 * qi + 1]   = bp.y;
        out[2 * N_Q + qi] = ts[bg];
    }
}

extern "C" void kernel_launch(void* const* d_in, const int* in_sizes, int n_in,
                              void* d_out, int out_size, void* d_ws, size_t ws_size,
                              hipStream_t stream) {
    const float* q    = (const float*)d_in[0];  // euclidean_data [N,2]
    const float* maze = (const float*)d_in[1];  // maze_points   [M,2]
    const float* ts   = (const float*)d_in[2];  // ts_proj       [M]
    float* out = (float*)d_out;                 // [N*2] proj_pos ++ [N] linear_pos

    if (ws_size >= (size_t)WS_NEED) {
        build_grid<<<1, 1024, 0, stream>>>(maze, ts, (float*)d_ws);
        grid_query<<<(N_Q + 255) / 256, 256, 0, stream>>>(q, (float*)d_ws, out);
        brute_overflow<<<256, 256, 0, stream>>>(q, maze, ts, (const float*)d_ws, out);
    } else {
        setup_soa<<<(NPAD + 255) / 256, 256, 0, stream>>>(maze, (float*)d_ws);
        nn_scan<<<(N_Q + 63) / 64, 256, 0, stream>>>(q, maze, ts,
                                                     (const float*)d_ws, out);
    }
}